// Round 3
// baseline (1257.868 us; speedup 1.0000x reference)
//
#include <hip/hip_runtime.h>
#include <stdint.h>
#include <stddef.h>

#define NEGF (-1.0e30f)

typedef __attribute__((ext_vector_type(2))) _Float16 half2_t;
typedef uint32_t u32x8 __attribute__((ext_vector_type(8)));

constexpr int Bn = 32;
constexpr int Tn = 2000;
constexpr int Cn = 256;
constexpr int Un = 200;
constexpr int Sn = 2 * Un + 1;  // 401 extended states
constexpr float Kn = 4096.0f;   // den normalization target

// f16 pair dot with fp32 accumulate: c += a.x*b.x + a.y*b.y
__device__ __forceinline__ float fdot2f(uint32_t a, uint32_t b, float c) {
  half2_t ha = __builtin_bit_cast(half2_t, a);
  half2_t hb = __builtin_bit_cast(half2_t, b);
#if __has_builtin(__builtin_amdgcn_fdot2)
  return __builtin_amdgcn_fdot2(ha, hb, c, false);
#else
  return c + (float)ha.x * (float)hb.x + (float)ha.y * (float)hb.y;
#endif
}

template <int CTRL>
__device__ __forceinline__ float dppf(float x) {
#if __has_builtin(__builtin_amdgcn_update_dpp)
  int xi = __builtin_bit_cast(int, x);
  int y = __builtin_amdgcn_update_dpp(0, xi, CTRL, 0xF, 0xF, false);
  return __builtin_bit_cast(float, y);
#else
  return x;
#endif
}
#define dpp_x1(v) dppf<0xB1>(v)    // quad_perm(1,0,3,2): lane ^ 1
#define dpp_x2(v) dppf<0x4E>(v)    // quad_perm(2,3,0,1): lane ^ 2
#define dpp_x7(v) dppf<0x141>(v)   // row_half_mirror:    lane ^ 7
#define dpp_x15(v) dppf<0x140>(v)  // row_mirror:         lane ^ 15

__device__ __forceinline__ uint32_t packe(float a, float b) {
  half2_t h;
  h.x = (_Float16)a;
  h.y = (_Float16)b;
  return __builtin_bit_cast(uint32_t, h);
}

__device__ __forceinline__ uint32_t paddh2(uint32_t a, uint32_t b) {
  half2_t r = __builtin_bit_cast(half2_t, a) + __builtin_bit_cast(half2_t, b);
  return __builtin_bit_cast(uint32_t, r);
}

__device__ __forceinline__ float lse3(float a, float b, float c) {
  float m = fmaxf(fmaxf(a, b), c);
  return m + __logf(__expf(a - m) + __expf(b - m) + __expf(c - m));
}

__device__ __forceinline__ int clampi(int v, int lo, int hi) {
  return v < lo ? lo : (v > hi ? hi : v);
}

// Barrier WITHOUT the vmcnt(0) drain __syncthreads() emits (round-3).
// Only LDS (lgkmcnt) must drain for cross-wave ds_write visibility; the
// compiler still inserts counted vmcnt(N) before each prefetch USE.
__device__ __forceinline__ void barrier_nodrain() {
  asm volatile("s_waitcnt lgkmcnt(0)" ::: "memory");
  __builtin_amdgcn_s_barrier();
  asm volatile("" ::: "memory");
}

// 64 blocks x 512 threads (8 waves, 2/SIMD). Blocks [0,32): den. [32,64): num.
//
// Round-5 rationale:
//  * den 16-row x 8-col split: E = 64 VGPR (round-1's 8x u32x16 = 128 VGPR
//    exceeded VGPR_Count=132 -> E partly AGPR-resident, accvgpr_read staging
//    on every dot ~ the unexplained ~450 cyc/step). Reads drop to 32B/lane
//    (16KB/step/CU, 4-lane broadcast per address) vs round-4's 32KB.
//  * num alpha in registers: neighbors via __shfl_up + 2-float/wave LDS
//    boundary double-buffer. Removes 3 exposed ds_reads + 400-float LDS
//    write per step from the critical path.
__global__ __launch_bounds__(512)
__attribute__((amdgpu_waves_per_eu(2, 2)))
void fwd_kernel(
    const float* __restrict__ logp, const int* __restrict__ targets,
    const int* __restrict__ in_lens, const int* __restrict__ tgt_lens,
    const float* __restrict__ trans, const float* __restrict__ start,
    float* __restrict__ ws) {
  const int tid = threadIdx.x;
  const int bid = blockIdx.x;

  if (bid < Bn) {
    // ============ denominator forward, exp domain, 16i x 8col tile ============
    // q = tid&15: i-chunk [16q,16q+16). u = tid>>4 in [0,32): cols {u+32k}.
    const int b = bid;
    const int L = clampi(in_lens[b], Sn, Tn);
    const int q = tid & 15;
    const int u = tid >> 4;
    const bool b3 = (q & 8) != 0, b2 = (q & 4) != 0, b1 = (q & 2) != 0;
    const int kk = (q >> 1);     // column-group this lane owns after reduce
    const int jw = u + 32 * kk;  // column owned (duplicated across ^1 pair)

    // 16 chunks x 32B at 80B stride (16-aligned for b128). Banks 20q%32:
    // only (q,q+8) alias -> 2-way, free per m136. Reads are 4-lane broadcast.
    __shared__ __align__(16) char eaLDS[2 * 16 * 80];
    __shared__ float sred[8];

    const float* trow = trans;
#define EP(c, m) packe(__expf(trow[(16 * q + 2 * (m)) * Cn + (c)]), \
                       __expf(trow[(16 * q + 2 * (m) + 1) * Cn + (c)]))
#define MKCOL(c)                                                 \
  (u32x8){EP(c, 0), EP(c, 1), EP(c, 2), EP(c, 3),                \
          EP(c, 4), EP(c, 5), EP(c, 6), EP(c, 7)}
    u32x8 E0 = MKCOL(u + 0);
    u32x8 E1 = MKCOL(u + 32);
    u32x8 E2 = MKCOL(u + 64);
    u32x8 E3 = MKCOL(u + 96);
    u32x8 E4 = MKCOL(u + 128);
    u32x8 E5 = MKCOL(u + 160);
    u32x8 E6 = MKCOL(u + 192);
    u32x8 E7 = MKCOL(u + 224);
#undef MKCOL
#undef EP

    const float* lpb = logp + (size_t)b * Tn * Cn;
    const char* rbase0 = eaLDS + 80 * q;  // this lane's 32B read chunk
    // write slot for column jw: chunk jw>>4 = (u>>4)+2*kk, slot jw&15 = u&15
    char* wptr0 = eaLDS + 80 * ((u >> 4) + 2 * kk) + 2 * (u & 15);

    // t = 0: stored = K * exp(start + lp0); G carries the log scale.
    float G = -__logf(Kn);
    if (tid < 256) {
      const int c = tid;
      *(_Float16*)(eaLDS + 80 * (c >> 4) + 2 * (c & 15)) =
          (_Float16)(Kn * __expf(start[c] + lpb[c]));
    }
    // 2-deep emission prefetch (L >= Sn = 401, frame 2 always exists).
    float lp0 = lpb[Cn + jw];              // t = 1
    float lp1 = lpb[(size_t)2 * Cn + jw];  // t = 2
    __syncthreads();

    const uint32_t ONE2 = 0x3C003C00u;  // f16 (1.0, 1.0)

    for (int t = 1; t < L; ++t) {
      const int pr = (t - 1) & 1, pw = t & 1;
      const float lp_cur = lp0;
      lp0 = lp1;
      const int tpre = (t + 2 < L) ? t + 2 : L - 1;
      lp1 = lpb[(size_t)tpre * Cn + jw];  // prefetch frame t+2
      const float p = __expf(lp_cur);

      const uint4* eap = (const uint4*)(rbase0 + pr * 1280);
      const uint4 ea0 = eap[0];
      const uint4 ea1 = eap[1];
      float a0 = 0.f, a1 = 0.f, a2 = 0.f, a3 = 0.f;
      float a4 = 0.f, a5 = 0.f, a6 = 0.f, a7 = 0.f;
#define DOT8(idx, ev)            \
  a0 = fdot2f(E0[idx], ev, a0);  \
  a1 = fdot2f(E1[idx], ev, a1);  \
  a2 = fdot2f(E2[idx], ev, a2);  \
  a3 = fdot2f(E3[idx], ev, a3);  \
  a4 = fdot2f(E4[idx], ev, a4);  \
  a5 = fdot2f(E5[idx], ev, a5);  \
  a6 = fdot2f(E6[idx], ev, a6);  \
  a7 = fdot2f(E7[idx], ev, a7);
      DOT8(0, ea0.x)
      DOT8(1, ea0.y)
      DOT8(2, ea0.z)
      DOT8(3, ea0.w)
      DOT8(4, ea1.x)
      DOT8(5, ea1.y)
      DOT8(6, ea1.z)
      DOT8(7, ea1.w)
#undef DOT8

      // Z = Sigma_i ea_i: this lane's chunk sum (f16 tree) -> 16-lane reduce.
      uint32_t zt = paddh2(paddh2(ea0.x, ea0.y), paddh2(ea0.z, ea0.w));
      zt = paddh2(zt, paddh2(paddh2(ea1.x, ea1.y), paddh2(ea1.z, ea1.w)));
      float zc = fdot2f(ONE2, zt, 0.f);
      zc += dpp_x1(zc);
      zc += dpp_x2(zc);
      zc += dpp_x7(zc);
      zc += dpp_x15(zc);  // all 16 q-lanes now hold full Z (block-uniform)

      // column reduce over the 16-lane q-group, give/keep halving exchange:
      // S1 (^15, split k-bit2 by q-bit3), S2 (^7, k-bit1 by q-bit2),
      // S3 (^2, k-bit0 by q-bit1), S4 (^1 plain butterfly: same column).
      float g, r0, r1, r2, r3, w0, w1, v, s;
      g = b3 ? a0 : a4;  r0 = (b3 ? a4 : a0) + dpp_x15(g);
      g = b3 ? a1 : a5;  r1 = (b3 ? a5 : a1) + dpp_x15(g);
      g = b3 ? a2 : a6;  r2 = (b3 ? a6 : a2) + dpp_x15(g);
      g = b3 ? a3 : a7;  r3 = (b3 ? a7 : a3) + dpp_x15(g);
      g = b2 ? r0 : r2;  w0 = (b2 ? r2 : r0) + dpp_x7(g);
      g = b2 ? r1 : r3;  w1 = (b2 ? r3 : r1) + dpp_x7(g);
      g = b1 ? w0 : w1;  v  = (b1 ? w1 : w0) + dpp_x2(g);
      s = v + dpp_x1(v);
      // lane (u,q) holds full s for column jw = u + 32*(q>>1); the ^1 pair
      // holds identical values -> duplicate same-addr same-value write is ok.

      const float invZ = Kn * __frcp_rn(zc);
      G -= __logf(invZ);
      *(_Float16*)(wptr0 + pw * 1280) = (_Float16)(s * p * invZ);
      barrier_nodrain();
    }

    // den[b] = G + log(Sigma_j stored_j)
    {
      const int pL = (L - 1) & 1;
      const char* fb = eaLDS + pL * 1280;
      float e = 0.f;
      if (tid < 256)
        e = (float)(*(const _Float16*)(fb + 80 * (tid >> 4) + 2 * (tid & 15)));
#pragma unroll
      for (int off = 32; off >= 1; off >>= 1) e += __shfl_xor(e, off, 64);
      const int lane = tid & 63, wid = tid >> 6;
      if (lane == 0) sred[wid] = e;
      __syncthreads();
      if (tid == 0) {
        float ssum = ((sred[0] + sred[1]) + (sred[2] + sred[3])) +
                     ((sred[4] + sred[5]) + (sred[6] + sred[7]));
        ws[Bn + b] = G + __logf(ssum);
      }
    }
  } else {
    // ================= CTC numerator forward (log domain) =================
    // alpha in registers, one state per thread. Neighbors s-1/s-2 via
    // __shfl_up; wave boundaries via 2-float/wave double-buffered LDS.
    const int b = bid - Bn;
    const int L = clampi(in_lens[b], Sn, Tn);
    const int tl = clampi(tgt_lens[b], 1, Un);

    __shared__ float bound[2][8][2];  // [buf][wave][lane62,lane63]
    __shared__ float afin[Sn];
    const float* lpb = logp + (size_t)b * Tn * Cn;
    const int* tgtb = targets + b * Un;

    const int s = tid;
    const int w = tid >> 6, lane = tid & 63;
    const bool act = (s < Sn);
    int e1 = 0;
    bool k1 = false;
    if (act && (s & 1)) {
      const int uu = (s - 1) >> 1;
      e1 = clampi(tgtb[uu], 1, Cn - 1);
      if (uu > 0) k1 = (e1 != clampi(tgtb[uu - 1], 1, Cn - 1));
    }

    // t = 0 init
    float aS = NEGF;
    if (act) aS = (s == 0) ? lpb[0] : (s == 1 ? lpb[e1] : NEGF);
    if (lane == 62) bound[0][w][0] = aS;
    if (lane == 63) bound[0][w][1] = aS;
    // 2-deep emission prefetch (addresses t-invariant per thread).
    float pe0 = lpb[Cn + e1];              // t = 1
    float pe1 = lpb[(size_t)2 * Cn + e1];  // t = 2 (L >= 401)
    __syncthreads();

    for (int t = 1; t < L; ++t) {
      const int pr = (t - 1) & 1, pw = t & 1;
      const float em = pe0;
      pe0 = pe1;
      const int tpre = (t + 2 < L) ? t + 2 : L - 1;
      pe1 = lpb[(size_t)tpre * Cn + e1];

      float y = __shfl_up(aS, 1, 64);  // alpha[s-1]
      float z = __shfl_up(aS, 2, 64);  // alpha[s-2]
      if (lane == 0) {
        y = (w > 0) ? bound[pr][w - 1][1] : NEGF;
        z = (w > 0) ? bound[pr][w - 1][0] : NEGF;
      } else if (lane == 1) {
        z = (w > 0) ? bound[pr][w - 1][1] : NEGF;
      }
      const float zm = k1 ? z : NEGF;  // k1 false for blanks/repeats/s<2
      float nv = lse3(aS, y, zm) + em;
      if (act) aS = nv;  // inactive lanes stay NEG
      if (lane == 62) bound[pw][w][0] = aS;
      if (lane == 63) bound[pw][w][1] = aS;
      barrier_nodrain();
    }
    if (act) afin[s] = aS;
    __syncthreads();
    if (tid == 0) {
      const int l = 2 * tl;
      const float x = afin[l], yv = afin[l - 1];
      const float m = fmaxf(x, yv);
      ws[b] = m + __logf(__expf(x - m) + __expf(yv - m));
    }
  }
}

__global__ void finalize_kernel(const float* __restrict__ ws,
                                float* __restrict__ out) {
  const int tid = threadIdx.x;  // 64 threads, one wave
  float tot = 0.f, cnt = 0.f;
  if (tid < Bn) {
    const float tv = ws[tid] - ws[Bn + tid];  // num - DEN_SCALE*den
    const bool valid = tv > 0.5f * NEGF;
    tot = valid ? tv : 0.f;
    cnt = valid ? 1.f : 0.f;
  }
#pragma unroll
  for (int off = 32; off >= 1; off >>= 1) {
    tot += __shfl_xor(tot, off, 64);
    cnt += __shfl_xor(cnt, off, 64);
  }
  if (tid == 0) out[0] = -tot / fmaxf(cnt, 1.f);
}

extern "C" void kernel_launch(void* const* d_in, const int* in_sizes, int n_in,
                              void* d_out, int out_size, void* d_ws, size_t ws_size,
                              hipStream_t stream) {
  const float* logp = (const float*)d_in[0];
  const int* targets = (const int*)d_in[1];
  const int* in_lens = (const int*)d_in[2];
  const int* tgt_lens = (const int*)d_in[3];
  const float* trans = (const float*)d_in[4];
  const float* start = (const float*)d_in[5];
  float* ws = (float*)d_ws;
  float* out = (float*)d_out;
  (void)in_sizes; (void)n_in; (void)out_size; (void)ws_size;

  fwd_kernel<<<dim3(2 * Bn), dim3(512), 0, stream>>>(
      logp, targets, in_lens, tgt_lens, trans, start, ws);
  finalize_kernel<<<dim3(1), dim3(64), 0, stream>>>(ws, out);
}